// Round 17
// baseline (127.635 us; speedup 1.0000x reference)
//
#include <hip/hip_runtime.h>

typedef unsigned int u32;
typedef unsigned short u16;
typedef __attribute__((ext_vector_type(8))) short short8;
typedef __attribute__((ext_vector_type(4))) float f32x4;
typedef __attribute__((ext_vector_type(2))) u32 u32x2;
typedef __attribute__((ext_vector_type(4))) u32 u32x4;

#define DEV __device__ __forceinline__

DEV u16 f2bf(float f) {
  u32 u = __builtin_bit_cast(u32, f);
  u = (u + 0x7FFFu + ((u >> 16) & 1u)) >> 16;
  return (u16)u;
}

DEV float fexp2(float x) {
#if __has_builtin(__builtin_amdgcn_exp2f)
  return __builtin_amdgcn_exp2f(x);
#else
  return exp2f(x);
#endif
}

DEV u32 cvt_pk_bf16(float lo, float hi) {
  u32 r;
  asm("v_cvt_pk_bf16_f32 %0, %1, %2" : "=v"(r) : "v"(lo), "v"(hi));
  return r;
}

// async global->LDS, 16B per lane; lds base must be wave-uniform.
DEV void llds16(const void* g, void* lds) {
  __builtin_amdgcn_global_load_lds(
      (const __attribute__((address_space(1))) u32*)g,
      (__attribute__((address_space(3))) u32*)lds, 16, 0, 0);
}

// ---------------- f32 -> bf16 conversion, weights only (4 x 1M elems) ----------------
struct CvtW {
  const float* src[4];
  u16* dst[4];
};

__global__ void cvt_w(CvtW cw) {
  int i = blockIdx.x * blockDim.x + threadIdx.x;  // 8-elem group, 0..524287
  int seg = i >> 17;
  size_t off = ((size_t)(i & 131071)) * 8;
  const f32x4* p = (const f32x4*)(cw.src[seg] + off);
  f32x4 a = p[0], b = p[1];
  u32x4 o;
  o[0] = cvt_pk_bf16(a[0], a[1]);
  o[1] = cvt_pk_bf16(a[2], a[3]);
  o[2] = cvt_pk_bf16(b[0], b[1]);
  o[3] = cvt_pk_bf16(b[2], b[3]);
  *(u32x4*)(cw.dst[seg] + off) = o;
}

// ---------------- GEMM: C[M,1024] = A[M,1024] @ W[1024,1024]^T + bias ----------------
// 1-D grid, XCD-aware bijective swizzle (A-panel + per-z W stay XCD-L2-resident).
// BK=64; LDS tiles laid out like the ATTENTION K-tile (measured 0 bank conflicts):
// row stride 128B, element at global k-byte cb stored at inner = cb ^ ((row&7)<<4).
// Staging: linear dest (DMA rule / linear cvt-writes) + pre-swizzled SOURCE column.
// Fragment read: row*128 + ((c*64 + lg*16) ^ ((row&7)<<4)), c = k-half.
// A_F32: fused f32->bf16 A staging with R13's cross-step register prefetch.
struct GemmArgs {
  const void* A[3];
  const u16* W[3];
  const float* bias[3];
  void* C[3];
  float scale[3];
};

template <int BM, int BN, int WAVES_M, int OUT_BF16, int NB_M, int A_F32>
__global__ __launch_bounds__(256, 2) void gemm_bt(GemmArgs ga) {
  constexpr int K = 1024, N = 1024;
  constexpr int WAVES_N = 4 / WAVES_M;
  constexpr int WM = BM / WAVES_M, WN = BN / WAVES_N;
  constexpr int AM = WM / 16, AN = WN / 16;

  __shared__ u16 lsA[BM * 64];
  __shared__ u16 lsB[BN * 64];

  // XCD-aware swizzle (grid divisible by 8; bijective)
  const u32 orig = blockIdx.x;
  const u32 nid = (orig & 7u) * (gridDim.x >> 3) + (orig >> 3);
  const int bn = (int)(nid & 7u);
  const int bm = (int)((nid >> 3) % (u32)NB_M);
  const int z = (int)((nid >> 3) / (u32)NB_M);

  const u16* __restrict__ W = ga.W[z];
  const int tid = threadIdx.x;
  const int l = tid & 63, w = tid >> 6;
  const int lg = l >> 4, lr = l & 15;
  const int wm = w / WAVES_N, wn = w % WAVES_N;

  f32x4 acc[AM][AN];
#pragma unroll
  for (int i = 0; i < AM; ++i)
#pragma unroll
    for (int j = 0; j < AN; ++j) acc[i][j] = (f32x4){0.f, 0.f, 0.f, 0.f};

// stage one 1KB seg (8 rows x 128B) of a tile; linear LDS dest, swizzled source col
#define STAGE_SEG(MAT, ROWBASE, LSX, SB, K0)                                    \
  {                                                                             \
    u32 lb = (u32)(SB) + l * 16;                                                \
    u32 row = lb >> 7;                                                          \
    u32 inner = (lb & 127) ^ ((row & 7) << 4);                                  \
    llds16((MAT) + (size_t)((ROWBASE) + row) * K + (K0) + (inner >> 1),         \
           (char*)(LSX) + (SB));                                                \
  }
#define FRAG_MFMA()                                                             \
  {                                                                             \
    _Pragma("unroll") for (int c = 0; c < 2; ++c) {                             \
      short8 af[AM], bf[AN];                                                    \
      _Pragma("unroll") for (int i = 0; i < AM; ++i) {                          \
        u32 ar = (u32)(wm * WM + i * 16 + lr);                                  \
        af[i] = *(const short8*)((const char*)lsA + ar * 128 +                  \
                 (((u32)(c * 64) + (u32)(lg * 16)) ^ ((ar & 7) << 4)));         \
      }                                                                         \
      _Pragma("unroll") for (int j = 0; j < AN; ++j) {                          \
        u32 br = (u32)(wn * WN + j * 16 + lr);                                  \
        bf[j] = *(const short8*)((const char*)lsB + br * 128 +                  \
                 (((u32)(c * 64) + (u32)(lg * 16)) ^ ((br & 7) << 4)));         \
      }                                                                         \
      _Pragma("unroll") for (int i = 0; i < AM; ++i)                            \
      _Pragma("unroll") for (int j = 0; j < AN; ++j)                            \
        acc[i][j] = __builtin_amdgcn_mfma_f32_16x16x32_bf16(af[i], bf[j],       \
                                                            acc[i][j], 0, 0, 0); \
    }                                                                           \
  }

  if constexpr (A_F32) {
    // BM=128: A tile 16KB = 16 segs, 4 per wave; per seg thread owns 16B slot
    const float* __restrict__ Af = (const float*)ga.A[z];
    const float* srcA[4];
    u32 lbA[4];
#pragma unroll
    for (int i = 0; i < 4; ++i) {
      u32 lb = (u32)(w * 4 + i) * 1024 + l * 16;
      u32 row = lb >> 7;
      u32 inner = (lb & 127) ^ ((row & 7) << 4);
      lbA[i] = lb;
      srcA[i] = Af + (size_t)(bm * BM + row) * K + (inner >> 1);
    }
    f32x4 ca[4][2], na[4][2];
#pragma unroll
    for (int i = 0; i < 4; ++i) {
      ca[i][0] = *(const f32x4*)(srcA[i]);
      ca[i][1] = *(const f32x4*)(srcA[i] + 4);
    }

#define GSTEP(K0, CUR, NXT)                                                     \
  {                                                                             \
    __syncthreads();                                                            \
    _Pragma("unroll") for (int i = 0; i < 4; ++i)                               \
      STAGE_SEG(W, bn * BN, lsB, (w * 4 + i) * 1024, (K0));                     \
    _Pragma("unroll") for (int i = 0; i < 4; ++i) {                             \
      u32x4 o;                                                                  \
      o[0] = cvt_pk_bf16(CUR[i][0][0], CUR[i][0][1]);                           \
      o[1] = cvt_pk_bf16(CUR[i][0][2], CUR[i][0][3]);                           \
      o[2] = cvt_pk_bf16(CUR[i][1][0], CUR[i][1][1]);                           \
      o[3] = cvt_pk_bf16(CUR[i][1][2], CUR[i][1][3]);                           \
      *(u32x4*)((char*)lsA + lbA[i]) = o;                                       \
    }                                                                           \
    if ((K0) + 64 < K) {                                                        \
      _Pragma("unroll") for (int i = 0; i < 4; ++i) {                           \
        NXT[i][0] = *(const f32x4*)(srcA[i] + (K0) + 64);                       \
        NXT[i][1] = *(const f32x4*)(srcA[i] + (K0) + 68);                       \
      }                                                                         \
    }                                                                           \
    __syncthreads();                                                            \
    FRAG_MFMA();                                                                \
  }

    for (int kk = 0; kk < K; kk += 128) {
      GSTEP(kk, ca, na);
      GSTEP(kk + 64, na, ca);
    }
#undef GSTEP
  } else {
    const u16* __restrict__ A = (const u16*)ga.A[z];
    constexpr int SEGS = (BM + BN) / 8;  // 1KB segs (8 rows x 128B)
    constexpr int PW = SEGS / 4;
    for (int k0 = 0; k0 < K; k0 += 64) {
      __syncthreads();
#pragma unroll
      for (int i = 0; i < PW; ++i) {
        int s = w * PW + i;  // wave-uniform
        if (s < BM / 8) {
          STAGE_SEG(A, bm * BM, lsA, s * 1024, k0);
        } else {
          STAGE_SEG(W, bn * BN, lsB, (s - BM / 8) * 1024, k0);
        }
      }
      __syncthreads();
      FRAG_MFMA();
    }
  }
#undef STAGE_SEG
#undef FRAG_MFMA

  const float sc = ga.scale[z];
  const float* __restrict__ bias = ga.bias[z];
#pragma unroll
  for (int j = 0; j < AN; ++j) {
    int col = bn * BN + wn * WN + j * 16 + lr;
    float bv = bias[col];
#pragma unroll
    for (int i = 0; i < AM; ++i) {
      int row0 = bm * BM + wm * WM + i * 16 + lg * 4;
#pragma unroll
      for (int r = 0; r < 4; ++r) {
        float v = (acc[i][j][r] + bv) * sc;
        if constexpr (OUT_BF16)
          ((u16*)ga.C[z])[(size_t)(row0 + r) * N + col] = f2bf(v);
        else
          ((float*)ga.C[z])[(size_t)(row0 + r) * N + col] = v;
      }
    }
  }
}

// ---------------- flash attention (QK-ahead software pipeline, P in-register) ----------------
// Q pre-scaled by log2(e)/8. Layouts: [B*S][1024], head h at cols h*64..h*64+63.
// 4 waves x 32 q-rows = 128 q/block; quad-buffered K/V tiles (R9 structure, 57.2us).
__global__ __launch_bounds__(256, 2) void attn_fwd(
    const u16* __restrict__ Q, const u16* __restrict__ Kp,
    const u16* __restrict__ V, u16* __restrict__ O) {
  constexpr int S = 2048, LD = 1024;
  __shared__ u16 Kt[4][64 * 64];  // [key][d], byte ^= ((key&7)<<4)
  __shared__ u16 Vt[4][64 * 64];  // [d][kp] (kp = pi-slot), byte ^= ((d&7)<<4)
  const int tid = threadIdx.x;
  const int l = tid & 63, w = tid >> 6;
  const int lg = l >> 4, lr = l & 15;

  const u32 orig = blockIdx.x;  // 0..511
  const u32 nid = (orig & 7u) * 64u + (orig >> 3);
  const int qt = (int)(nid & 15u);
  const int h = (int)((nid >> 4) & 15u);
  const int b = (int)(nid >> 8);

  const size_t base = ((size_t)b * S) * LD + h * 64;
  const int q0 = qt * 128 + w * 32;  // wave's rows: q0 + g*16 + lr

  short8 qf[2][2];
#pragma unroll
  for (int g = 0; g < 2; ++g)
#pragma unroll
    for (int c = 0; c < 2; ++c)
      qf[g][c] = *(const short8*)&Q[base + (size_t)(q0 + g * 16 + lr) * LD + c * 32 + lg * 8];

  f32x4 acc[2][4];
#pragma unroll
  for (int g = 0; g < 2; ++g)
#pragma unroll
    for (int i = 0; i < 4; ++i) acc[g][i] = (f32x4){0.f, 0.f, 0.f, 0.f};
  float lsum[2] = {0.f, 0.f};

  // V-repack thread mapping: slot pair kp0=2m holds keys key0, key0+1 (pi-permuted)
  const int m = tid & 31;
  const int kp0 = m * 2;
  const int key0 = ((m & 16) << 1) + ((m & 2) << 3) + (((m >> 2) & 3) << 2) + ((m & 1) << 1);
  const int vd0 = (tid >> 5) * 8;

#define KSTAGE(T)                                                               \
  {                                                                             \
    _Pragma("unroll") for (int i_ = 0; i_ < 2; ++i_) {                          \
      u32 sb = (u32)(w * 2 + i_) * 1024;                                        \
      u32 lb = sb + l * 16;                                                     \
      u32 key = lb >> 7;                                                        \
      u32 inner = (lb & 127) ^ ((key & 7) << 4);                                \
      llds16(Kp + base + (size_t)((T) * 64 + key) * LD + (inner >> 1),          \
             (char*)Kt[(T) & 3] + sb);                                          \
    }                                                                           \
  }
#define VLOAD(T, VA, VB)                                                        \
  {                                                                             \
    VA = *(const short8*)&V[base + (size_t)((T) * 64 + key0) * LD + vd0];       \
    VB = *(const short8*)&V[base + (size_t)((T) * 64 + key0 + 1) * LD + vd0];   \
  }
#define VWRITE(T, VA, VB)                                                       \
  {                                                                             \
    _Pragma("unroll") for (int jj = 0; jj < 8; ++jj) {                          \
      u32 pv = (u32)(u16)(VA)[jj] | ((u32)(u16)(VB)[jj] << 16);                 \
      u32 addr = (u32)((vd0 + jj) * 128 + kp0 * 2) ^ ((u32)jj << 4);            \
      *(u32*)((char*)Vt[(T) & 3] + addr) = pv;                                  \
    }                                                                           \
  }
// QK: S^T = K.Q^T for tile T into SV; lane owns q-row (g*16+lr), keys ks*16+lg*4+{0..3}
#define QK(T, SV)                                                               \
  {                                                                             \
    __builtin_amdgcn_s_setprio(1);                                              \
    _Pragma("unroll") for (int ks = 0; ks < 4; ++ks) {                          \
      u32 a0 = (u32)(((ks * 16 + lr) * 128 + lg * 16) ^ ((lr & 7) << 4));       \
      short8 kf0 = *(const short8*)((const char*)Kt[(T) & 3] + a0);             \
      short8 kf1 = *(const short8*)((const char*)Kt[(T) & 3] + (a0 ^ 64));      \
      _Pragma("unroll") for (int g = 0; g < 2; ++g) {                           \
        f32x4 s_ = (f32x4){0.f, 0.f, 0.f, 0.f};                                 \
        s_ = __builtin_amdgcn_mfma_f32_16x16x32_bf16(kf0, qf[g][0], s_, 0, 0, 0); \
        s_ = __builtin_amdgcn_mfma_f32_16x16x32_bf16(kf1, qf[g][1], s_, 0, 0, 0); \
        SV[g][ks] = s_;                                                         \
      }                                                                         \
    }                                                                           \
    __builtin_amdgcn_s_setprio(0);                                              \
  }
// SM: exp2 + pack SV -> PK, accumulate lsum
#define SM(SV, PK)                                                              \
  {                                                                             \
    _Pragma("unroll") for (int g = 0; g < 2; ++g) {                             \
      _Pragma("unroll") for (int ks = 0; ks < 4; ++ks) {                        \
        float e0 = fexp2(SV[g][ks][0]), e1 = fexp2(SV[g][ks][1]);               \
        float e2 = fexp2(SV[g][ks][2]), e3 = fexp2(SV[g][ks][3]);               \
        lsum[g] += (e0 + e1) + (e2 + e3);                                       \
        PK[g][ks * 2 + 0] = cvt_pk_bf16(e0, e1);                                \
        PK[g][ks * 2 + 1] = cvt_pk_bf16(e2, e3);                                \
      }                                                                         \
    }                                                                           \
  }
// PV: ctx^T += V^T.P^T for tile T (A = Vt pi-ordered, B = PK words)
#define PV(T, PK)                                                               \
  {                                                                             \
    __builtin_amdgcn_s_setprio(1);                                              \
    _Pragma("unroll") for (int ds = 0; ds < 4; ++ds) {                          \
      _Pragma("unroll") for (int c = 0; c < 2; ++c) {                           \
        u32 va_ = (u32)(((ds * 16 + lr) * 128 + c * 64 + lg * 16) ^ ((lr & 7) << 4)); \
        short8 vf = *(const short8*)((const char*)Vt[(T) & 3] + va_);           \
        _Pragma("unroll") for (int g = 0; g < 2; ++g) {                         \
          u32x4 pc = {PK[g][c * 4 + 0], PK[g][c * 4 + 1], PK[g][c * 4 + 2], PK[g][c * 4 + 3]}; \
          short8 pf = __builtin_bit_cast(short8, pc);                           \
          acc[g][ds] = __builtin_amdgcn_mfma_f32_16x16x32_bf16(vf, pf, acc[g][ds], 0, 0, 0); \
        }                                                                       \
      }                                                                         \
    }                                                                           \
    __builtin_amdgcn_s_setprio(0);                                              \
  }
// One pipeline iteration. On entry: SVC = QK(t); Kt[(t+1)&3] resident; Vt[t&3]
// resident; (VCA,VCB) hold V(t+1) values. Produces SVN = QK(t+1), (VNA,VNB) = V(t+2).
#define ITER(t, SVC, SVN, VCA, VCB, VNA, VNB)                                   \
  {                                                                             \
    if ((t) < 30) { VLOAD((t) + 2, VNA, VNB); KSTAGE((t) + 2); }                \
    if ((t) < 31) QK((t) + 1, SVN);                                             \
    u32 pk_[2][8];                                                              \
    SM(SVC, pk_);                                                               \
    if ((t) < 31) VWRITE((t) + 1, VCA, VCB);                                    \
    PV(t, pk_);                                                                 \
    __syncthreads();                                                            \
  }

  f32x4 svA[2][4], svB[2][4];
  short8 vaA, vbA, vaB, vbB;

  // prologue: stage tiles 0,1; VWRITE(0); barrier; QK(0)
  VLOAD(0, vaB, vbB); KSTAGE(0);
  VLOAD(1, vaA, vbA); KSTAGE(1);
  VWRITE(0, vaB, vbB);
  __syncthreads();
  QK(0, svA);

  for (int tt = 0; tt < 16; ++tt) {
    ITER(2 * tt, svA, svB, vaA, vbA, vaB, vbB);
    ITER(2 * tt + 1, svB, svA, vaB, vbB, vaA, vbA);
  }

  // row-sums: lanes lg=0..3 hold disjoint key subsets of row lr
#pragma unroll
  for (int g = 0; g < 2; ++g) {
    lsum[g] += __shfl_xor(lsum[g], 16);
    lsum[g] += __shfl_xor(lsum[g], 32);
  }
#pragma unroll
  for (int g = 0; g < 2; ++g) {
    float inv = __builtin_amdgcn_rcpf(lsum[g]);
#pragma unroll
    for (int ds = 0; ds < 4; ++ds) {
      u32x2 ov;
      ov[0] = cvt_pk_bf16(acc[g][ds][0] * inv, acc[g][ds][1] * inv);
      ov[1] = cvt_pk_bf16(acc[g][ds][2] * inv, acc[g][ds][3] * inv);
      *(u32x2*)&O[base + (size_t)(q0 + g * 16 + lr) * LD + ds * 16 + lg * 4] = ov;
    }
  }
#undef KSTAGE
#undef VLOAD
#undef VWRITE
#undef QK
#undef SM
#undef PV
#undef ITER
}

// ---------------- launcher ----------------
extern "C" void kernel_launch(void* const* d_in, const int* in_sizes, int n_in,
                              void* d_out, int out_size, void* d_ws, size_t ws_size,
                              hipStream_t stream) {
  constexpr size_t SZ_X = 4096ull * 1024;  // activation elements
  constexpr size_t SZ_W = 1024ull * 1024;  // weight elements
  const float* bq = (const float*)d_in[4];
  const float* bk = (const float*)d_in[6];
  const float* bv = (const float*)d_in[8];
  const float* bo = (const float*)d_in[10];

  char* ws = (char*)d_ws;
  u16* wqb = (u16*)ws;
  u16* wkb = wqb + SZ_W;
  u16* wvb = wkb + SZ_W;
  u16* wob = wvb + SZ_W;
  u16* Qp = wob + SZ_W;
  u16* Kp = Qp + SZ_X;
  u16* Vp = Kp + SZ_X;
  u16* Cx = Vp + SZ_X;  // total ws use: 40 MB

  CvtW cw;
  cw.src[0] = (const float*)d_in[3]; cw.dst[0] = wqb;
  cw.src[1] = (const float*)d_in[5]; cw.dst[1] = wkb;
  cw.src[2] = (const float*)d_in[7]; cw.dst[2] = wvb;
  cw.src[3] = (const float*)d_in[9]; cw.dst[3] = wob;
  cvt_w<<<dim3(2048), 256, 0, stream>>>(cw);

  GemmArgs g1;
  g1.A[0] = d_in[0]; g1.A[1] = d_in[1]; g1.A[2] = d_in[2];  // f32 activations
  g1.W[0] = wqb; g1.W[1] = wkb; g1.W[2] = wvb;
  g1.bias[0] = bq; g1.bias[1] = bk; g1.bias[2] = bv;
  g1.C[0] = Qp; g1.C[1] = Kp; g1.C[2] = Vp;
  g1.scale[0] = 0.18033688011112042f;  // log2(e)/8 folded into Q
  g1.scale[1] = 1.f; g1.scale[2] = 1.f;
  gemm_bt<128, 128, 2, 1, 32, 1><<<dim3(768), 256, 0, stream>>>(g1);

  attn_fwd<<<dim3(512), 256, 0, stream>>>(Qp, Kp, Vp, Cx);

  GemmArgs g2 = {};
  g2.A[0] = Cx; g2.W[0] = wob; g2.bias[0] = bo; g2.C[0] = d_out; g2.scale[0] = 1.f;
  gemm_bt<64, 128, 1, 0, 64, 0><<<dim3(512), 256, 0, stream>>>(g2);
}

// Round 18
// 120.542 us; speedup vs baseline: 1.0588x; 1.0588x over previous
//
#include <hip/hip_runtime.h>

typedef unsigned int u32;
typedef unsigned short u16;
typedef __attribute__((ext_vector_type(8))) short short8;
typedef __attribute__((ext_vector_type(4))) float f32x4;
typedef __attribute__((ext_vector_type(2))) u32 u32x2;
typedef __attribute__((ext_vector_type(4))) u32 u32x4;

#define DEV __device__ __forceinline__

DEV u16 f2bf(float f) {
  u32 u = __builtin_bit_cast(u32, f);
  u = (u + 0x7FFFu + ((u >> 16) & 1u)) >> 16;
  return (u16)u;
}

DEV float fexp2(float x) {
#if __has_builtin(__builtin_amdgcn_exp2f)
  return __builtin_amdgcn_exp2f(x);
#else
  return exp2f(x);
#endif
}

DEV u32 cvt_pk_bf16(float lo, float hi) {
  u32 r;
  asm("v_cvt_pk_bf16_f32 %0, %1, %2" : "=v"(r) : "v"(lo), "v"(hi));
  return r;
}

// async global->LDS, 16B per lane; lds base must be wave-uniform.
DEV void llds16(const void* g, void* lds) {
  __builtin_amdgcn_global_load_lds(
      (const __attribute__((address_space(1))) u32*)g,
      (__attribute__((address_space(3))) u32*)lds, 16, 0, 0);
}

// ---------------- f32 -> bf16 conversion, weights only (4 x 1M elems) ----------------
struct CvtW {
  const float* src[4];
  u16* dst[4];
};

__global__ void cvt_w(CvtW cw) {
  int i = blockIdx.x * blockDim.x + threadIdx.x;  // 8-elem group, 0..524287
  int seg = i >> 17;
  size_t off = ((size_t)(i & 131071)) * 8;
  const f32x4* p = (const f32x4*)(cw.src[seg] + off);
  f32x4 a = p[0], b = p[1];
  u32x4 o;
  o[0] = cvt_pk_bf16(a[0], a[1]);
  o[1] = cvt_pk_bf16(a[2], a[3]);
  o[2] = cvt_pk_bf16(b[0], b[1]);
  o[3] = cvt_pk_bf16(b[2], b[3]);
  *(u32x4*)(cw.dst[seg] + off) = o;
}

// ---------------- GEMM: C[M,1024] = A[M,1024] @ W[1024,1024]^T + bias ----------------
// 1-D grid, XCD-aware bijective swizzle; bn fastest within an XCD chunk so each
// XCD sweeps one A-panel across all bn while its per-z W (2MB) stays L2-resident.
// A_F32 (BM=BN=128 only): A is f32 in global; fused f32->bf16 during staging.
// Each lane owns LINEAR LDS slot seg*1024 + l*16 (DMA-identical, conflict-free)
// and decodes its global (row,col) source from it.
// KEY SCHEDULING FIX (R18): the A-prefetch for step k+1 is issued AFTER the
// second barrier, so its latency hides under frag-reads + MFMA and is drained
// at the NEXT step's first barrier (covered) — not at this step's bar2 (exposed).
struct GemmArgs {
  const void* A[3];
  const u16* W[3];
  const float* bias[3];
  void* C[3];
  float scale[3];
};

template <int BM, int BN, int WAVES_M, int OUT_BF16, int NB_M, int A_F32>
__global__ __launch_bounds__(256, 2) void gemm_bt(GemmArgs ga) {
  constexpr int K = 1024, N = 1024;
  constexpr int WAVES_N = 4 / WAVES_M;
  constexpr int WM = BM / WAVES_M, WN = BN / WAVES_N;
  constexpr int AM = WM / 16, AN = WN / 16;

  __shared__ u16 lsA[BM * 32];
  __shared__ u16 lsB[BN * 32];

  // XCD-aware swizzle (grid divisible by 8; bijective)
  const u32 orig = blockIdx.x;
  const u32 nid = (orig & 7u) * (gridDim.x >> 3) + (orig >> 3);
  const int bn = (int)(nid & 7u);
  const int bm = (int)((nid >> 3) % (u32)NB_M);
  const int z = (int)((nid >> 3) / (u32)NB_M);

  const u16* __restrict__ W = ga.W[z];
  const int tid = threadIdx.x;
  const int l = tid & 63, w = tid >> 6;
  const int lg = l >> 4, lr = l & 15;
  const int wm = w / WAVES_N, wn = w % WAVES_N;

  f32x4 acc[AM][AN];
#pragma unroll
  for (int i = 0; i < AM; ++i)
#pragma unroll
    for (int j = 0; j < AN; ++j) acc[i][j] = (f32x4){0.f, 0.f, 0.f, 0.f};

  if constexpr (A_F32) {
    const float* __restrict__ Af = (const float*)ga.A[z];
    // lane's two linear A slots: lb = (w*2+i)*1024 + l*16
    // decode: row = lb>>6, f32 col = (lb&63)>>1 (8 consecutive f32)
    const u32 lb0 = (u32)(w * 2 + 0) * 1024 + l * 16;
    const u32 lb1 = (u32)(w * 2 + 1) * 1024 + l * 16;
    const float* src0 = Af + (size_t)(bm * BM + (lb0 >> 6)) * K + ((lb0 & 63) >> 1);
    const float* src1 = Af + (size_t)(bm * BM + (lb1 >> 6)) * K + ((lb1 & 63) >> 1);

    f32x4 pa0, pa1, pb0, pb1;
    pa0 = *(const f32x4*)src0; pa1 = *(const f32x4*)(src0 + 4);
    pb0 = *(const f32x4*)src1; pb1 = *(const f32x4*)(src1 + 4);

    for (int k0 = 0; k0 < K; k0 += 32) {
      __syncthreads();  // bar1: drains last step's prefetch (covered by MFMA time)
      // W via DMA: 8 segs, 2 per wave
#pragma unroll
      for (int i = 0; i < 2; ++i) {
        u32 sb = (u32)(w * 2 + i) * 1024;
        u32 lbw = sb + l * 16;
        u32 row = lbw >> 6, colS = (lbw & 63) >> 1;
        llds16(W + (size_t)(bn * BN + row) * K + k0 + colS, (char*)lsB + sb);
      }
      // cvt + conflict-free linear writes (regs prefetched a full step ago)
      {
        u32x4 o;
        o[0] = cvt_pk_bf16(pa0[0], pa0[1]); o[1] = cvt_pk_bf16(pa0[2], pa0[3]);
        o[2] = cvt_pk_bf16(pa1[0], pa1[1]); o[3] = cvt_pk_bf16(pa1[2], pa1[3]);
        *(u32x4*)((char*)lsA + lb0) = o;
        o[0] = cvt_pk_bf16(pb0[0], pb0[1]); o[1] = cvt_pk_bf16(pb0[2], pb0[3]);
        o[2] = cvt_pk_bf16(pb1[0], pb1[1]); o[3] = cvt_pk_bf16(pb1[2], pb1[3]);
        *(u32x4*)((char*)lsA + lb1) = o;
      }
      __syncthreads();  // bar2: drains only the W-DMA (covered by cvt time)
      // prefetch next step's A AFTER bar2 — flies during frag reads + MFMA
      if (k0 + 32 < K) {
        pa0 = *(const f32x4*)(src0 + k0 + 32); pa1 = *(const f32x4*)(src0 + k0 + 36);
        pb0 = *(const f32x4*)(src1 + k0 + 32); pb1 = *(const f32x4*)(src1 + k0 + 36);
      }
      short8 af[AM], bf[AN];
#pragma unroll
      for (int i = 0; i < AM; ++i)
        af[i] = *(const short8*)&lsA[(wm * WM + i * 16 + lr) * 32 + lg * 8];
#pragma unroll
      for (int j = 0; j < AN; ++j)
        bf[j] = *(const short8*)&lsB[(wn * WN + j * 16 + lr) * 32 + lg * 8];
#pragma unroll
      for (int i = 0; i < AM; ++i)
#pragma unroll
        for (int j = 0; j < AN; ++j)
          acc[i][j] = __builtin_amdgcn_mfma_f32_16x16x32_bf16(af[i], bf[j], acc[i][j], 0, 0, 0);
    }
  } else {
    const u16* __restrict__ A = (const u16*)ga.A[z];
    constexpr int SEGS = (BM + BN) / 16;
    constexpr int PW = SEGS / 4;
    for (int k0 = 0; k0 < K; k0 += 32) {
      __syncthreads();
#pragma unroll
      for (int i = 0; i < PW; ++i) {
        int s = w * PW + i;  // wave-uniform
        if (s < BM / 16) {
          u32 sb = s * 1024;
          u32 lb = sb + l * 16;
          u32 row = lb >> 6, colS = (lb & 63) >> 1;
          llds16(A + (size_t)(bm * BM + row) * K + k0 + colS, (char*)lsA + sb);
        } else {
          u32 sb = (u32)(s - BM / 16) * 1024;
          u32 lb = sb + l * 16;
          u32 row = lb >> 6, colS = (lb & 63) >> 1;
          llds16(W + (size_t)(bn * BN + row) * K + k0 + colS, (char*)lsB + sb);
        }
      }
      __syncthreads();
      short8 af[AM], bf[AN];
#pragma unroll
      for (int i = 0; i < AM; ++i)
        af[i] = *(const short8*)&lsA[(wm * WM + i * 16 + lr) * 32 + lg * 8];
#pragma unroll
      for (int j = 0; j < AN; ++j)
        bf[j] = *(const short8*)&lsB[(wn * WN + j * 16 + lr) * 32 + lg * 8];
#pragma unroll
      for (int i = 0; i < AM; ++i)
#pragma unroll
        for (int j = 0; j < AN; ++j)
          acc[i][j] = __builtin_amdgcn_mfma_f32_16x16x32_bf16(af[i], bf[j], acc[i][j], 0, 0, 0);
    }
  }

  const float sc = ga.scale[z];
  const float* __restrict__ bias = ga.bias[z];
#pragma unroll
  for (int j = 0; j < AN; ++j) {
    int col = bn * BN + wn * WN + j * 16 + lr;
    float bv = bias[col];
#pragma unroll
    for (int i = 0; i < AM; ++i) {
      int row0 = bm * BM + wm * WM + i * 16 + lg * 4;
#pragma unroll
      for (int r = 0; r < 4; ++r) {
        float v = (acc[i][j][r] + bv) * sc;
        if constexpr (OUT_BF16)
          ((u16*)ga.C[z])[(size_t)(row0 + r) * N + col] = f2bf(v);
        else
          ((float*)ga.C[z])[(size_t)(row0 + r) * N + col] = v;
      }
    }
  }
}

// ---------------- flash attention (QK-ahead software pipeline, P in-register) ----------------
// Q pre-scaled by log2(e)/8. Layouts: [B*S][1024], head h at cols h*64..h*64+63.
// 4 waves x 32 q-rows = 128 q/block; quad-buffered K/V tiles (R9 structure, 57.2us).
__global__ __launch_bounds__(256, 2) void attn_fwd(
    const u16* __restrict__ Q, const u16* __restrict__ Kp,
    const u16* __restrict__ V, u16* __restrict__ O) {
  constexpr int S = 2048, LD = 1024;
  __shared__ u16 Kt[4][64 * 64];  // [key][d], byte ^= ((key&7)<<4)
  __shared__ u16 Vt[4][64 * 64];  // [d][kp] (kp = pi-slot), byte ^= ((d&7)<<4)
  const int tid = threadIdx.x;
  const int l = tid & 63, w = tid >> 6;
  const int lg = l >> 4, lr = l & 15;

  const u32 orig = blockIdx.x;  // 0..511
  const u32 nid = (orig & 7u) * 64u + (orig >> 3);
  const int qt = (int)(nid & 15u);
  const int h = (int)((nid >> 4) & 15u);
  const int b = (int)(nid >> 8);

  const size_t base = ((size_t)b * S) * LD + h * 64;
  const int q0 = qt * 128 + w * 32;  // wave's rows: q0 + g*16 + lr

  short8 qf[2][2];
#pragma unroll
  for (int g = 0; g < 2; ++g)
#pragma unroll
    for (int c = 0; c < 2; ++c)
      qf[g][c] = *(const short8*)&Q[base + (size_t)(q0 + g * 16 + lr) * LD + c * 32 + lg * 8];

  f32x4 acc[2][4];
#pragma unroll
  for (int g = 0; g < 2; ++g)
#pragma unroll
    for (int i = 0; i < 4; ++i) acc[g][i] = (f32x4){0.f, 0.f, 0.f, 0.f};
  float lsum[2] = {0.f, 0.f};

  // V-repack thread mapping: slot pair kp0=2m holds keys key0, key0+1 (pi-permuted)
  const int m = tid & 31;
  const int kp0 = m * 2;
  const int key0 = ((m & 16) << 1) + ((m & 2) << 3) + (((m >> 2) & 3) << 2) + ((m & 1) << 1);
  const int vd0 = (tid >> 5) * 8;

#define KSTAGE(T)                                                               \
  {                                                                             \
    _Pragma("unroll") for (int i_ = 0; i_ < 2; ++i_) {                          \
      u32 sb = (u32)(w * 2 + i_) * 1024;                                        \
      u32 lb = sb + l * 16;                                                     \
      u32 key = lb >> 7;                                                        \
      u32 inner = (lb & 127) ^ ((key & 7) << 4);                                \
      llds16(Kp + base + (size_t)((T) * 64 + key) * LD + (inner >> 1),          \
             (char*)Kt[(T) & 3] + sb);                                          \
    }                                                                           \
  }
#define VLOAD(T, VA, VB)                                                        \
  {                                                                             \
    VA = *(const short8*)&V[base + (size_t)((T) * 64 + key0) * LD + vd0];       \
    VB = *(const short8*)&V[base + (size_t)((T) * 64 + key0 + 1) * LD + vd0];   \
  }
#define VWRITE(T, VA, VB)                                                       \
  {                                                                             \
    _Pragma("unroll") for (int jj = 0; jj < 8; ++jj) {                          \
      u32 pv = (u32)(u16)(VA)[jj] | ((u32)(u16)(VB)[jj] << 16);                 \
      u32 addr = (u32)((vd0 + jj) * 128 + kp0 * 2) ^ ((u32)jj << 4);            \
      *(u32*)((char*)Vt[(T) & 3] + addr) = pv;                                  \
    }                                                                           \
  }
// QK: S^T = K.Q^T for tile T into SV; lane owns q-row (g*16+lr), keys ks*16+lg*4+{0..3}
#define QK(T, SV)                                                               \
  {                                                                             \
    __builtin_amdgcn_s_setprio(1);                                              \
    _Pragma("unroll") for (int ks = 0; ks < 4; ++ks) {                          \
      u32 a0 = (u32)(((ks * 16 + lr) * 128 + lg * 16) ^ ((lr & 7) << 4));       \
      short8 kf0 = *(const short8*)((const char*)Kt[(T) & 3] + a0);             \
      short8 kf1 = *(const short8*)((const char*)Kt[(T) & 3] + (a0 ^ 64));      \
      _Pragma("unroll") for (int g = 0; g < 2; ++g) {                           \
        f32x4 s_ = (f32x4){0.f, 0.f, 0.f, 0.f};                                 \
        s_ = __builtin_amdgcn_mfma_f32_16x16x32_bf16(kf0, qf[g][0], s_, 0, 0, 0); \
        s_ = __builtin_amdgcn_mfma_f32_16x16x32_bf16(kf1, qf[g][1], s_, 0, 0, 0); \
        SV[g][ks] = s_;                                                         \
      }                                                                         \
    }                                                                           \
    __builtin_amdgcn_s_setprio(0);                                              \
  }
// SM: exp2 + pack SV -> PK, accumulate lsum
#define SM(SV, PK)                                                              \
  {                                                                             \
    _Pragma("unroll") for (int g = 0; g < 2; ++g) {                             \
      _Pragma("unroll") for (int ks = 0; ks < 4; ++ks) {                        \
        float e0 = fexp2(SV[g][ks][0]), e1 = fexp2(SV[g][ks][1]);               \
        float e2 = fexp2(SV[g][ks][2]), e3 = fexp2(SV[g][ks][3]);               \
        lsum[g] += (e0 + e1) + (e2 + e3);                                       \
        PK[g][ks * 2 + 0] = cvt_pk_bf16(e0, e1);                                \
        PK[g][ks * 2 + 1] = cvt_pk_bf16(e2, e3);                                \
      }                                                                         \
    }                                                                           \
  }
// PV: ctx^T += V^T.P^T for tile T (A = Vt pi-ordered, B = PK words)
#define PV(T, PK)                                                               \
  {                                                                             \
    __builtin_amdgcn_s_setprio(1);                                              \
    _Pragma("unroll") for (int ds = 0; ds < 4; ++ds) {                          \
      _Pragma("unroll") for (int c = 0; c < 2; ++c) {                           \
        u32 va_ = (u32)(((ds * 16 + lr) * 128 + c * 64 + lg * 16) ^ ((lr & 7) << 4)); \
        short8 vf = *(const short8*)((const char*)Vt[(T) & 3] + va_);           \
        _Pragma("unroll") for (int g = 0; g < 2; ++g) {                         \
          u32x4 pc = {PK[g][c * 4 + 0], PK[g][c * 4 + 1], PK[g][c * 4 + 2], PK[g][c * 4 + 3]}; \
          short8 pf = __builtin_bit_cast(short8, pc);                           \
          acc[g][ds] = __builtin_amdgcn_mfma_f32_16x16x32_bf16(vf, pf, acc[g][ds], 0, 0, 0); \
        }                                                                       \
      }                                                                         \
    }                                                                           \
    __builtin_amdgcn_s_setprio(0);                                              \
  }
// One pipeline iteration. On entry: SVC = QK(t); Kt[(t+1)&3] resident; Vt[t&3]
// resident; (VCA,VCB) hold V(t+1) values. Produces SVN = QK(t+1), (VNA,VNB) = V(t+2).
#define ITER(t, SVC, SVN, VCA, VCB, VNA, VNB)                                   \
  {                                                                             \
    if ((t) < 30) { VLOAD((t) + 2, VNA, VNB); KSTAGE((t) + 2); }                \
    if ((t) < 31) QK((t) + 1, SVN);                                             \
    u32 pk_[2][8];                                                              \
    SM(SVC, pk_);                                                               \
    if ((t) < 31) VWRITE((t) + 1, VCA, VCB);                                    \
    PV(t, pk_);                                                                 \
    __syncthreads();                                                            \
  }

  f32x4 svA[2][4], svB[2][4];
  short8 vaA, vbA, vaB, vbB;

  // prologue: stage tiles 0,1; VWRITE(0); barrier; QK(0)
  VLOAD(0, vaB, vbB); KSTAGE(0);
  VLOAD(1, vaA, vbA); KSTAGE(1);
  VWRITE(0, vaB, vbB);
  __syncthreads();
  QK(0, svA);

  for (int tt = 0; tt < 16; ++tt) {
    ITER(2 * tt, svA, svB, vaA, vbA, vaB, vbB);
    ITER(2 * tt + 1, svB, svA, vaB, vbB, vaA, vbA);
  }

  // row-sums: lanes lg=0..3 hold disjoint key subsets of row lr
#pragma unroll
  for (int g = 0; g < 2; ++g) {
    lsum[g] += __shfl_xor(lsum[g], 16);
    lsum[g] += __shfl_xor(lsum[g], 32);
  }
#pragma unroll
  for (int g = 0; g < 2; ++g) {
    float inv = __builtin_amdgcn_rcpf(lsum[g]);
#pragma unroll
    for (int ds = 0; ds < 4; ++ds) {
      u32x2 ov;
      ov[0] = cvt_pk_bf16(acc[g][ds][0] * inv, acc[g][ds][1] * inv);
      ov[1] = cvt_pk_bf16(acc[g][ds][2] * inv, acc[g][ds][3] * inv);
      *(u32x2*)&O[base + (size_t)(q0 + g * 16 + lr) * LD + ds * 16 + lg * 4] = ov;
    }
  }
#undef KSTAGE
#undef VLOAD
#undef VWRITE
#undef QK
#undef SM
#undef PV
#undef ITER
}

// ---------------- launcher ----------------
extern "C" void kernel_launch(void* const* d_in, const int* in_sizes, int n_in,
                              void* d_out, int out_size, void* d_ws, size_t ws_size,
                              hipStream_t stream) {
  constexpr size_t SZ_X = 4096ull * 1024;  // activation elements
  constexpr size_t SZ_W = 1024ull * 1024;  // weight elements
  const float* bq = (const float*)d_in[4];
  const float* bk = (const float*)d_in[6];
  const float* bv = (const float*)d_in[8];
  const float* bo = (const float*)d_in[10];

  char* ws = (char*)d_ws;
  u16* wqb = (u16*)ws;
  u16* wkb = wqb + SZ_W;
  u16* wvb = wkb + SZ_W;
  u16* wob = wvb + SZ_W;
  u16* Qp = wob + SZ_W;
  u16* Kp = Qp + SZ_X;
  u16* Vp = Kp + SZ_X;
  u16* Cx = Vp + SZ_X;  // total ws use: 40 MB

  CvtW cw;
  cw.src[0] = (const float*)d_in[3]; cw.dst[0] = wqb;
  cw.src[1] = (const float*)d_in[5]; cw.dst[1] = wkb;
  cw.src[2] = (const float*)d_in[7]; cw.dst[2] = wvb;
  cw.src[3] = (const float*)d_in[9]; cw.dst[3] = wob;
  cvt_w<<<dim3(2048), 256, 0, stream>>>(cw);

  GemmArgs g1;
  g1.A[0] = d_in[0]; g1.A[1] = d_in[1]; g1.A[2] = d_in[2];  // f32 activations
  g1.W[0] = wqb; g1.W[1] = wkb; g1.W[2] = wvb;
  g1.bias[0] = bq; g1.bias[1] = bk; g1.bias[2] = bv;
  g1.C[0] = Qp; g1.C[1] = Kp; g1.C[2] = Vp;
  g1.scale[0] = 0.18033688011112042f;  // log2(e)/8 folded into Q
  g1.scale[1] = 1.f; g1.scale[2] = 1.f;
  gemm_bt<128, 128, 2, 1, 32, 1><<<dim3(768), 256, 0, stream>>>(g1);

  attn_fwd<<<dim3(512), 256, 0, stream>>>(Qp, Kp, Vp, Cx);

  GemmArgs g2 = {};
  g2.A[0] = Cx; g2.W[0] = wob; g2.bias[0] = bo; g2.C[0] = d_out; g2.scale[0] = 1.f;
  gemm_bt<64, 128, 1, 0, 64, 0><<<dim3(512), 256, 0, stream>>>(g2);
}

// Round 19
// 118.296 us; speedup vs baseline: 1.0789x; 1.0190x over previous
//
#include <hip/hip_runtime.h>

typedef unsigned int u32;
typedef unsigned short u16;
typedef __attribute__((ext_vector_type(8))) short short8;
typedef __attribute__((ext_vector_type(4))) float f32x4;
typedef __attribute__((ext_vector_type(2))) u32 u32x2;
typedef __attribute__((ext_vector_type(4))) u32 u32x4;

#define DEV __device__ __forceinline__

DEV u16 f2bf(float f) {
  u32 u = __builtin_bit_cast(u32, f);
  u = (u + 0x7FFFu + ((u >> 16) & 1u)) >> 16;
  return (u16)u;
}

DEV float fexp2(float x) {
#if __has_builtin(__builtin_amdgcn_exp2f)
  return __builtin_amdgcn_exp2f(x);
#else
  return exp2f(x);
#endif
}

DEV u32 cvt_pk_bf16(float lo, float hi) {
  u32 r;
  asm("v_cvt_pk_bf16_f32 %0, %1, %2" : "=v"(r) : "v"(lo), "v"(hi));
  return r;
}

// async global->LDS, 16B per lane; lds base must be wave-uniform.
DEV void llds16(const void* g, void* lds) {
  __builtin_amdgcn_global_load_lds(
      (const __attribute__((address_space(1))) u32*)g,
      (__attribute__((address_space(3))) u32*)lds, 16, 0, 0);
}

// ---------------- f32 -> bf16 conversion, weights only (4 x 1M elems) ----------------
struct CvtW {
  const float* src[4];
  u16* dst[4];
};

__global__ void cvt_w(CvtW cw) {
  int i = blockIdx.x * blockDim.x + threadIdx.x;  // 8-elem group, 0..524287
  int seg = i >> 17;
  size_t off = ((size_t)(i & 131071)) * 8;
  const f32x4* p = (const f32x4*)(cw.src[seg] + off);
  f32x4 a = p[0], b = p[1];
  u32x4 o;
  o[0] = cvt_pk_bf16(a[0], a[1]);
  o[1] = cvt_pk_bf16(a[2], a[3]);
  o[2] = cvt_pk_bf16(b[0], b[1]);
  o[3] = cvt_pk_bf16(b[2], b[3]);
  *(u32x4*)(cw.dst[seg] + off) = o;
}

// ---------------- GEMM: C[M,1024] = A[M,1024] @ W[1024,1024]^T + bias ----------------
// 1-D grid, XCD-aware bijective swizzle (A-panel + per-z W stay XCD-L2-resident).
// R19: LDS DOUBLE-BUFFER, one barrier per K-step. Iteration t stages tile t+1
// (W via DMA, A via reg-cvt) into buf^1 BEFORE the MFMA on buf, so the barrier's
// implicit vmcnt drain sits after ~32 MFMAs + frag reads (~400cyc cover) instead
// of immediately after issue (the R13/R18 exposed-drain defect).
// A_F32: fused f32->bf16 A staging, reg ping-pong loaded one step ahead.
struct GemmArgs {
  const void* A[3];
  const u16* W[3];
  const float* bias[3];
  void* C[3];
  float scale[3];
};

template <int BM, int BN, int WAVES_M, int OUT_BF16, int NB_M, int A_F32>
__global__ __launch_bounds__(256, 2) void gemm_bt(GemmArgs ga) {
  constexpr int K = 1024, N = 1024;
  constexpr int WAVES_N = 4 / WAVES_M;
  constexpr int WM = BM / WAVES_M, WN = BN / WAVES_N;
  constexpr int AM = WM / 16, AN = WN / 16;

  __shared__ u16 lsA[2][BM * 32];
  __shared__ u16 lsB[2][BN * 32];

  // XCD-aware swizzle (grid divisible by 8; bijective)
  const u32 orig = blockIdx.x;
  const u32 nid = (orig & 7u) * (gridDim.x >> 3) + (orig >> 3);
  const int bn = (int)(nid & 7u);
  const int bm = (int)((nid >> 3) % (u32)NB_M);
  const int z = (int)((nid >> 3) / (u32)NB_M);

  const u16* __restrict__ W = ga.W[z];
  const int tid = threadIdx.x;
  const int l = tid & 63, w = tid >> 6;
  const int lg = l >> 4, lr = l & 15;
  const int wm = w / WAVES_N, wn = w % WAVES_N;

  f32x4 acc[AM][AN];
#pragma unroll
  for (int i = 0; i < AM; ++i)
#pragma unroll
    for (int j = 0; j < AN; ++j) acc[i][j] = (f32x4){0.f, 0.f, 0.f, 0.f};

// W tile (BN rows x 32k) via DMA into LSX: BN/64 segs per wave
#define WDMA(K0, LSX)                                                           \
  {                                                                             \
    _Pragma("unroll") for (int i_ = 0; i_ < BN / 64; ++i_) {                    \
      u32 sb = (u32)(w * (BN / 64) + i_) * 1024;                                \
      u32 lbw = sb + l * 16;                                                    \
      u32 row = lbw >> 6, colS = (lbw & 63) >> 1;                               \
      llds16(W + (size_t)(bn * BN + row) * K + (K0) + colS, (char*)(LSX) + sb); \
    }                                                                           \
  }
#define FRAG_MFMA(LA, LB)                                                       \
  {                                                                             \
    short8 af[AM], bf[AN];                                                      \
    _Pragma("unroll") for (int i = 0; i < AM; ++i)                              \
      af[i] = *(const short8*)&(LA)[(wm * WM + i * 16 + lr) * 32 + lg * 8];     \
    _Pragma("unroll") for (int j = 0; j < AN; ++j)                              \
      bf[j] = *(const short8*)&(LB)[(wn * WN + j * 16 + lr) * 32 + lg * 8];     \
    _Pragma("unroll") for (int i = 0; i < AM; ++i)                              \
    _Pragma("unroll") for (int j = 0; j < AN; ++j)                              \
      acc[i][j] = __builtin_amdgcn_mfma_f32_16x16x32_bf16(af[i], bf[j],         \
                                                          acc[i][j], 0, 0, 0); \
  }

  if constexpr (A_F32) {
    const float* __restrict__ Af = (const float*)ga.A[z];
    // lane's two linear A slots: lb = (w*2+i)*1024 + l*16
    const u32 lb0 = (u32)(w * 2 + 0) * 1024 + l * 16;
    const u32 lb1 = (u32)(w * 2 + 1) * 1024 + l * 16;
    const float* src0 = Af + (size_t)(bm * BM + (lb0 >> 6)) * K + ((lb0 & 63) >> 1);
    const float* src1 = Af + (size_t)(bm * BM + (lb1 >> 6)) * K + ((lb1 & 63) >> 1);

#define ACVT(PA0, PA1, PB0, PB1, LSX)                                           \
  {                                                                             \
    u32x4 o;                                                                    \
    o[0] = cvt_pk_bf16(PA0[0], PA0[1]); o[1] = cvt_pk_bf16(PA0[2], PA0[3]);     \
    o[2] = cvt_pk_bf16(PA1[0], PA1[1]); o[3] = cvt_pk_bf16(PA1[2], PA1[3]);     \
    *(u32x4*)((char*)(LSX) + lb0) = o;                                          \
    o[0] = cvt_pk_bf16(PB0[0], PB0[1]); o[1] = cvt_pk_bf16(PB0[2], PB0[3]);     \
    o[2] = cvt_pk_bf16(PB1[0], PB1[1]); o[3] = cvt_pk_bf16(PB1[2], PB1[3]);     \
    *(u32x4*)((char*)(LSX) + lb1) = o;                                          \
  }
#define ALOAD(K0, PA0, PA1, PB0, PB1)                                           \
  {                                                                             \
    PA0 = *(const f32x4*)(src0 + (K0));     PA1 = *(const f32x4*)(src0 + (K0) + 4); \
    PB0 = *(const f32x4*)(src1 + (K0));     PB1 = *(const f32x4*)(src1 + (K0) + 4); \
  }

    f32x4 cA0, cA1, cB0, cB1, nA0, nA1, nB0, nB1;
    // prologue: tile 0 -> buf0 (W-DMA + A cvt); regs for tile 1
    WDMA(0, lsB[0]);
    ALOAD(0, cA0, cA1, cB0, cB1);
    ACVT(cA0, cA1, cB0, cB1, lsA[0]);
    ALOAD(32, nA0, nA1, nB0, nB1);
    __syncthreads();

    for (int kk = 0; kk < K; kk += 64) {
      // iter A: compute buf0 (k=kk); stage k=kk+32 -> buf1; load k=kk+64
      if (kk + 32 < K) {
        WDMA(kk + 32, lsB[1]);
        ACVT(nA0, nA1, nB0, nB1, lsA[1]);
      }
      if (kk + 64 < K) ALOAD(kk + 64, cA0, cA1, cB0, cB1);
      FRAG_MFMA(lsA[0], lsB[0]);
      __syncthreads();
      // iter B: compute buf1 (k=kk+32); stage k=kk+64 -> buf0; load k=kk+96
      if (kk + 64 < K) {
        WDMA(kk + 64, lsB[0]);
        ACVT(cA0, cA1, cB0, cB1, lsA[0]);
      }
      if (kk + 96 < K) ALOAD(kk + 96, nA0, nA1, nB0, nB1);
      FRAG_MFMA(lsA[1], lsB[1]);
      __syncthreads();
    }
#undef ACVT
#undef ALOAD
  } else {
    const u16* __restrict__ A = (const u16*)ga.A[z];
    constexpr int SEGS = (BM + BN) / 16;
    constexpr int PW = SEGS / 4;
#define STAGE_ALL(K0, LA, LB)                                                   \
  {                                                                             \
    _Pragma("unroll") for (int i_ = 0; i_ < PW; ++i_) {                         \
      int s = w * PW + i_; /* wave-uniform */                                   \
      if (s < BM / 16) {                                                        \
        u32 sb = s * 1024;                                                      \
        u32 lb = sb + l * 16;                                                   \
        u32 row = lb >> 6, colS = (lb & 63) >> 1;                               \
        llds16(A + (size_t)(bm * BM + row) * K + (K0) + colS, (char*)(LA) + sb); \
      } else {                                                                  \
        u32 sb = (u32)(s - BM / 16) * 1024;                                     \
        u32 lb = sb + l * 16;                                                   \
        u32 row = lb >> 6, colS = (lb & 63) >> 1;                               \
        llds16(W + (size_t)(bn * BN + row) * K + (K0) + colS, (char*)(LB) + sb); \
      }                                                                         \
    }                                                                           \
  }
    // prologue: tile 0 -> buf0
    STAGE_ALL(0, lsA[0], lsB[0]);
    __syncthreads();
    for (int kk = 0; kk < K; kk += 64) {
      if (kk + 32 < K) STAGE_ALL(kk + 32, lsA[1], lsB[1]);
      FRAG_MFMA(lsA[0], lsB[0]);
      __syncthreads();
      if (kk + 64 < K) STAGE_ALL(kk + 64, lsA[0], lsB[0]);
      FRAG_MFMA(lsA[1], lsB[1]);
      __syncthreads();
    }
#undef STAGE_ALL
  }
#undef WDMA
#undef FRAG_MFMA

  const float sc = ga.scale[z];
  const float* __restrict__ bias = ga.bias[z];
#pragma unroll
  for (int j = 0; j < AN; ++j) {
    int col = bn * BN + wn * WN + j * 16 + lr;
    float bv = bias[col];
#pragma unroll
    for (int i = 0; i < AM; ++i) {
      int row0 = bm * BM + wm * WM + i * 16 + lg * 4;
#pragma unroll
      for (int r = 0; r < 4; ++r) {
        float v = (acc[i][j][r] + bv) * sc;
        if constexpr (OUT_BF16)
          ((u16*)ga.C[z])[(size_t)(row0 + r) * N + col] = f2bf(v);
        else
          ((float*)ga.C[z])[(size_t)(row0 + r) * N + col] = v;
      }
    }
  }
}

// ---------------- flash attention (QK-ahead software pipeline, P in-register) ----------------
// Q pre-scaled by log2(e)/8. Layouts: [B*S][1024], head h at cols h*64..h*64+63.
// 4 waves x 32 q-rows = 128 q/block; quad-buffered K/V tiles (R9 structure, 57.2us).
__global__ __launch_bounds__(256, 2) void attn_fwd(
    const u16* __restrict__ Q, const u16* __restrict__ Kp,
    const u16* __restrict__ V, u16* __restrict__ O) {
  constexpr int S = 2048, LD = 1024;
  __shared__ u16 Kt[4][64 * 64];  // [key][d], byte ^= ((key&7)<<4)
  __shared__ u16 Vt[4][64 * 64];  // [d][kp] (kp = pi-slot), byte ^= ((d&7)<<4)
  const int tid = threadIdx.x;
  const int l = tid & 63, w = tid >> 6;
  const int lg = l >> 4, lr = l & 15;

  const u32 orig = blockIdx.x;  // 0..511
  const u32 nid = (orig & 7u) * 64u + (orig >> 3);
  const int qt = (int)(nid & 15u);
  const int h = (int)((nid >> 4) & 15u);
  const int b = (int)(nid >> 8);

  const size_t base = ((size_t)b * S) * LD + h * 64;
  const int q0 = qt * 128 + w * 32;  // wave's rows: q0 + g*16 + lr

  short8 qf[2][2];
#pragma unroll
  for (int g = 0; g < 2; ++g)
#pragma unroll
    for (int c = 0; c < 2; ++c)
      qf[g][c] = *(const short8*)&Q[base + (size_t)(q0 + g * 16 + lr) * LD + c * 32 + lg * 8];

  f32x4 acc[2][4];
#pragma unroll
  for (int g = 0; g < 2; ++g)
#pragma unroll
    for (int i = 0; i < 4; ++i) acc[g][i] = (f32x4){0.f, 0.f, 0.f, 0.f};
  float lsum[2] = {0.f, 0.f};

  // V-repack thread mapping: slot pair kp0=2m holds keys key0, key0+1 (pi-permuted)
  const int m = tid & 31;
  const int kp0 = m * 2;
  const int key0 = ((m & 16) << 1) + ((m & 2) << 3) + (((m >> 2) & 3) << 2) + ((m & 1) << 1);
  const int vd0 = (tid >> 5) * 8;

#define KSTAGE(T)                                                               \
  {                                                                             \
    _Pragma("unroll") for (int i_ = 0; i_ < 2; ++i_) {                          \
      u32 sb = (u32)(w * 2 + i_) * 1024;                                        \
      u32 lb = sb + l * 16;                                                     \
      u32 key = lb >> 7;                                                        \
      u32 inner = (lb & 127) ^ ((key & 7) << 4);                                \
      llds16(Kp + base + (size_t)((T) * 64 + key) * LD + (inner >> 1),          \
             (char*)Kt[(T) & 3] + sb);                                          \
    }                                                                           \
  }
#define VLOAD(T, VA, VB)                                                        \
  {                                                                             \
    VA = *(const short8*)&V[base + (size_t)((T) * 64 + key0) * LD + vd0];       \
    VB = *(const short8*)&V[base + (size_t)((T) * 64 + key0 + 1) * LD + vd0];   \
  }
#define VWRITE(T, VA, VB)                                                       \
  {                                                                             \
    _Pragma("unroll") for (int jj = 0; jj < 8; ++jj) {                          \
      u32 pv = (u32)(u16)(VA)[jj] | ((u32)(u16)(VB)[jj] << 16);                 \
      u32 addr = (u32)((vd0 + jj) * 128 + kp0 * 2) ^ ((u32)jj << 4);            \
      *(u32*)((char*)Vt[(T) & 3] + addr) = pv;                                  \
    }                                                                           \
  }
// QK: S^T = K.Q^T for tile T into SV; lane owns q-row (g*16+lr), keys ks*16+lg*4+{0..3}
#define QK(T, SV)                                                               \
  {                                                                             \
    __builtin_amdgcn_s_setprio(1);                                              \
    _Pragma("unroll") for (int ks = 0; ks < 4; ++ks) {                          \
      u32 a0 = (u32)(((ks * 16 + lr) * 128 + lg * 16) ^ ((lr & 7) << 4));       \
      short8 kf0 = *(const short8*)((const char*)Kt[(T) & 3] + a0);             \
      short8 kf1 = *(const short8*)((const char*)Kt[(T) & 3] + (a0 ^ 64));      \
      _Pragma("unroll") for (int g = 0; g < 2; ++g) {                           \
        f32x4 s_ = (f32x4){0.f, 0.f, 0.f, 0.f};                                 \
        s_ = __builtin_amdgcn_mfma_f32_16x16x32_bf16(kf0, qf[g][0], s_, 0, 0, 0); \
        s_ = __builtin_amdgcn_mfma_f32_16x16x32_bf16(kf1, qf[g][1], s_, 0, 0, 0); \
        SV[g][ks] = s_;                                                         \
      }                                                                         \
    }                                                                           \
    __builtin_amdgcn_s_setprio(0);                                              \
  }
// SM: exp2 + pack SV -> PK, accumulate lsum
#define SM(SV, PK)                                                              \
  {                                                                             \
    _Pragma("unroll") for (int g = 0; g < 2; ++g) {                             \
      _Pragma("unroll") for (int ks = 0; ks < 4; ++ks) {                        \
        float e0 = fexp2(SV[g][ks][0]), e1 = fexp2(SV[g][ks][1]);               \
        float e2 = fexp2(SV[g][ks][2]), e3 = fexp2(SV[g][ks][3]);               \
        lsum[g] += (e0 + e1) + (e2 + e3);                                       \
        PK[g][ks * 2 + 0] = cvt_pk_bf16(e0, e1);                                \
        PK[g][ks * 2 + 1] = cvt_pk_bf16(e2, e3);                                \
      }                                                                         \
    }                                                                           \
  }
// PV: ctx^T += V^T.P^T for tile T (A = Vt pi-ordered, B = PK words)
#define PV(T, PK)                                                               \
  {                                                                             \
    __builtin_amdgcn_s_setprio(1);                                              \
    _Pragma("unroll") for (int ds = 0; ds < 4; ++ds) {                          \
      _Pragma("unroll") for (int c = 0; c < 2; ++c) {                           \
        u32 va_ = (u32)(((ds * 16 + lr) * 128 + c * 64 + lg * 16) ^ ((lr & 7) << 4)); \
        short8 vf = *(const short8*)((const char*)Vt[(T) & 3] + va_);           \
        _Pragma("unroll") for (int g = 0; g < 2; ++g) {                         \
          u32x4 pc = {PK[g][c * 4 + 0], PK[g][c * 4 + 1], PK[g][c * 4 + 2], PK[g][c * 4 + 3]}; \
          short8 pf = __builtin_bit_cast(short8, pc);                           \
          acc[g][ds] = __builtin_amdgcn_mfma_f32_16x16x32_bf16(vf, pf, acc[g][ds], 0, 0, 0); \
        }                                                                       \
      }                                                                         \
    }                                                                           \
    __builtin_amdgcn_s_setprio(0);                                              \
  }
// One pipeline iteration. On entry: SVC = QK(t); Kt[(t+1)&3] resident; Vt[t&3]
// resident; (VCA,VCB) hold V(t+1) values. Produces SVN = QK(t+1), (VNA,VNB) = V(t+2).
#define ITER(t, SVC, SVN, VCA, VCB, VNA, VNB)                                   \
  {                                                                             \
    if ((t) < 30) { VLOAD((t) + 2, VNA, VNB); KSTAGE((t) + 2); }                \
    if ((t) < 31) QK((t) + 1, SVN);                                             \
    u32 pk_[2][8];                                                              \
    SM(SVC, pk_);                                                               \
    if ((t) < 31) VWRITE((t) + 1, VCA, VCB);                                    \
    PV(t, pk_);                                                                 \
    __syncthreads();                                                            \
  }

  f32x4 svA[2][4], svB[2][4];
  short8 vaA, vbA, vaB, vbB;

  // prologue: stage tiles 0,1; VWRITE(0); barrier; QK(0)
  VLOAD(0, vaB, vbB); KSTAGE(0);
  VLOAD(1, vaA, vbA); KSTAGE(1);
  VWRITE(0, vaB, vbB);
  __syncthreads();
  QK(0, svA);

  for (int tt = 0; tt < 16; ++tt) {
    ITER(2 * tt, svA, svB, vaA, vbA, vaB, vbB);
    ITER(2 * tt + 1, svB, svA, vaB, vbB, vaA, vbA);
  }

  // row-sums: lanes lg=0..3 hold disjoint key subsets of row lr
#pragma unroll
  for (int g = 0; g < 2; ++g) {
    lsum[g] += __shfl_xor(lsum[g], 16);
    lsum[g] += __shfl_xor(lsum[g], 32);
  }
#pragma unroll
  for (int g = 0; g < 2; ++g) {
    float inv = __builtin_amdgcn_rcpf(lsum[g]);
#pragma unroll
    for (int ds = 0; ds < 4; ++ds) {
      u32x2 ov;
      ov[0] = cvt_pk_bf16(acc[g][ds][0] * inv, acc[g][ds][1] * inv);
      ov[1] = cvt_pk_bf16(acc[g][ds][2] * inv, acc[g][ds][3] * inv);
      *(u32x2*)&O[base + (size_t)(q0 + g * 16 + lr) * LD + ds * 16 + lg * 4] = ov;
    }
  }
#undef KSTAGE
#undef VLOAD
#undef VWRITE
#undef QK
#undef SM
#undef PV
#undef ITER
}

// ---------------- launcher ----------------
extern "C" void kernel_launch(void* const* d_in, const int* in_sizes, int n_in,
                              void* d_out, int out_size, void* d_ws, size_t ws_size,
                              hipStream_t stream) {
  constexpr size_t SZ_X = 4096ull * 1024;  // activation elements
  constexpr size_t SZ_W = 1024ull * 1024;  // weight elements
  const float* bq = (const float*)d_in[4];
  const float* bk = (const float*)d_in[6];
  const float* bv = (const float*)d_in[8];
  const float* bo = (const float*)d_in[10];

  char* ws = (char*)d_ws;
  u16* wqb = (u16*)ws;
  u16* wkb = wqb + SZ_W;
  u16* wvb = wkb + SZ_W;
  u16* wob = wvb + SZ_W;
  u16* Qp = wob + SZ_W;
  u16* Kp = Qp + SZ_X;
  u16* Vp = Kp + SZ_X;
  u16* Cx = Vp + SZ_X;  // total ws use: 40 MB

  CvtW cw;
  cw.src[0] = (const float*)d_in[3]; cw.dst[0] = wqb;
  cw.src[1] = (const float*)d_in[5]; cw.dst[1] = wkb;
  cw.src[2] = (const float*)d_in[7]; cw.dst[2] = wvb;
  cw.src[3] = (const float*)d_in[9]; cw.dst[3] = wob;
  cvt_w<<<dim3(2048), 256, 0, stream>>>(cw);

  GemmArgs g1;
  g1.A[0] = d_in[0]; g1.A[1] = d_in[1]; g1.A[2] = d_in[2];  // f32 activations
  g1.W[0] = wqb; g1.W[1] = wkb; g1.W[2] = wvb;
  g1.bias[0] = bq; g1.bias[1] = bk; g1.bias[2] = bv;
  g1.C[0] = Qp; g1.C[1] = Kp; g1.C[2] = Vp;
  g1.scale[0] = 0.18033688011112042f;  // log2(e)/8 folded into Q
  g1.scale[1] = 1.f; g1.scale[2] = 1.f;
  gemm_bt<128, 128, 2, 1, 32, 1><<<dim3(768), 256, 0, stream>>>(g1);

  attn_fwd<<<dim3(512), 256, 0, stream>>>(Qp, Kp, Vp, Cx);

  GemmArgs g2 = {};
  g2.A[0] = Cx; g2.W[0] = wob; g2.bias[0] = bo; g2.C[0] = d_out; g2.scale[0] = 1.f;
  gemm_bt<64, 128, 1, 0, 64, 0><<<dim3(512), 256, 0, stream>>>(g2);
}